// Round 18
// baseline (146.374 us; speedup 1.0000x reference)
//
#include <hip/hip_runtime.h>
#include <hip/hip_bf16.h>

typedef __attribute__((ext_vector_type(4))) float f32x4;
typedef __attribute__((ext_vector_type(8))) short bf16x8;

#define H 1024        // hidden / K
#define NTOT 1280     // nq*64 + nkv*64*2
#define BM 128
#define BN 128
#define BK 64
#define NKT 16        // H / BK
#define NTILES 10     // NTOT / BN

static __device__ __forceinline__ unsigned short f2bf(float f) {
    __hip_bfloat16 b = __float2bfloat16(f);
    return __builtin_bit_cast(unsigned short, b);
}

#define GLOAD_LDS16(g, l)                                                     \
    __builtin_amdgcn_global_load_lds(                                         \
        (const __attribute__((address_space(1))) void*)(g),                   \
        (__attribute__((address_space(3))) void*)(l), 16, 0, 0)

// ---------------------------------------------------------------------------
// Kernel 1 (merged prologue): blocks [0,nrms) RMSNorm x->h; blocks
// [nrms, nrms+320) build fused-scaled weights in MFMA FRAGMENT ORDER:
// fragment (n16, k32) = 1KB: lane l holds Bt[n16*16+(l&15)][k32*32+(l>>4)*8+j]
// at byte ((n16*32+k32)<<10) + l*16, where Bt[n][k] = (1+lnw[k])*W[k][n].
// (Fragment-order Bf verified correct in R11.)
// ---------------------------------------------------------------------------
__global__ __launch_bounds__(256) void k_pre(const float* __restrict__ x,
                                             const float* __restrict__ wq,
                                             const float* __restrict__ wk,
                                             const float* __restrict__ wv,
                                             const float* __restrict__ lnw,
                                             __hip_bfloat16* __restrict__ h,
                                             __hip_bfloat16* __restrict__ Bf,
                                             int nrms) {
    __shared__ float l[64][65];
    const int t = threadIdx.x;

    if ((int)blockIdx.x < nrms) {
        const int wave = t >> 6;
        const int lane = t & 63;
        const size_t row = (size_t)blockIdx.x * 4 + wave;

        const float4* xr = (const float4*)(x + row * H);
        float4 v[4];
        float ss = 0.f;
#pragma unroll
        for (int i = 0; i < 4; ++i) {
            v[i] = xr[lane + 64 * i];
            ss += v[i].x * v[i].x + v[i].y * v[i].y + v[i].z * v[i].z + v[i].w * v[i].w;
        }
#pragma unroll
        for (int o = 1; o < 64; o <<= 1) ss += __shfl_xor(ss, o);
        const float sc = rsqrtf(ss * (1.0f / H) + 1e-6f);

        ushort4* hr = (ushort4*)(h + row * H);
#pragma unroll
        for (int i = 0; i < 4; ++i) {
            ushort4 o4;
            o4.x = f2bf(v[i].x * sc);
            o4.y = f2bf(v[i].y * sc);
            o4.z = f2bf(v[i].z * sc);
            o4.w = f2bf(v[i].w * sc);
            hr[lane + 64 * i] = o4;
        }
    } else {
        const int b = (int)blockIdx.x - nrms;     // 0..319
        const int kt = b & 15;                    // 16 k-tiles of 64
        const int ntl = b >> 4;                   // 20 n-tiles of 64
        const int k0 = kt * 64, n0 = ntl * 64;
        const float* src; int ldn, nb;
        if (n0 < 1024)      { src = wq; ldn = 1024; nb = n0; }
        else if (n0 < 1152) { src = wk; ldn = 128;  nb = n0 - 1024; }
        else                { src = wv; ldn = 128;  nb = n0 - 1152; }
        const int nl = t & 63, kl = t >> 6;
#pragma unroll
        for (int i = 0; i < 16; ++i) {
            const int k = kl + i * 4;
            l[k][nl] = (1.0f + lnw[k0 + k]) * src[(size_t)(k0 + k) * ldn + nb + nl];
        }
        __syncthreads();
        // 8 fragments (4 n16 x 2 k32) x 64 lanes = 512 slots of 16B; 2/thread
#pragma unroll
        for (int s2 = 0; s2 < 2; ++s2) {
            const int s = t + s2 * 256;
            const int fi = s >> 6, lane = s & 63;
            const int n16l = fi & 3, k32l = fi >> 2;
            const int col = lane & 15, kq = lane >> 4;
            bf16x8 pk;
#pragma unroll
            for (int j = 0; j < 8; ++j)
                pk[j] = f2bf(l[k32l * 32 + kq * 8 + j][n16l * 16 + col]);
            const size_t fr = (size_t)(ntl * 4 + n16l) * 32 + (kt * 2 + k32l);
            *(bf16x8*)((char*)Bf + (fr << 10) + lane * 16) = pk;
        }
    }
}

// ---------------------------------------------------------------------------
// Kernel 2: GEMM out[M][1280] = h[M][1024] @ W.  (R18)
// B NEVER TOUCHES LDS: B-fragments are 1KB coalesced global loads from the
// fragment-ordered Bf (2.6MB, L2-resident), double-buffered in registers.
// LDS = A only, ring-2 x 16KB = 32KB/block. All 32 MFMAs/tile are pure
// register ops issued as one cluster, overlapping STAGE_A(kt+2) gloads and
// BLOAD(kt+1). Structure per tile:
//   vmcnt(4)  [forces B(kt)+A(kt); A(kt+1) stays in flight]; BAR
//   ds_read A frags (8 x b128); BLOAD(kt+1) (8 x 1KB)
//   lgkm(0)+fence; BAR   [all waves' A-reads done -> safe overwrite]
//   STAGE_A(cur, kt+2); prio1; 32 MFMA (regs only); prio0
// 2 blocks/CU (8 waves x ~190 regs), T2 swizzle on A, XCD chunking
// nt-fastest, grid 2560 = 5 exact rounds. Fixes R9 (uncoalesced B +
// vmcnt(0)/tile) and R11 (3-block contention).
// ---------------------------------------------------------------------------
__global__ __launch_bounds__(256, 2) void k_gemm(const __hip_bfloat16* __restrict__ A,
                                                 const __hip_bfloat16* __restrict__ Bf,
                                                 float* __restrict__ out, int rows) {
    __shared__ __align__(16) char smem[32768];  // 2 bufs x A 16KB

    const int tid = threadIdx.x;
    const int lane = tid & 63;
    const int wid = tid >> 6;
    const int wm = wid >> 1;   // 0..1 (64 rows each)
    const int wn = wid & 1;    // 0..1 (64 cols each)

    // bijective XCD chunk swizzle (2560 % 8 == 0), nt fastest
    const int cpx = gridDim.x >> 3;                 // 320
    const int wg = (blockIdx.x & 7) * cpx + (blockIdx.x >> 3);
    const int nt = wg % NTILES;
    const int mt = wg / NTILES;
    const size_t m0 = (size_t)mt * BM;

    // ---- A staging: thread t covers rows (t>>3)+q*32 (q=0..3), 16B at
    //      (t&7)*16, source col pre-swizzled ((row&7)<<4) (both-sides).
    const int r = tid >> 3;                         // 0..31
    const int cswz = ((tid & 7) * 16) ^ ((r & 7) << 4);
    const char* aG = (const char*)A + (m0 + r) * (size_t)(H * 2) + cswz;

#define STAGE_A(buf, kt)                                                      \
    _Pragma("unroll") for (int q = 0; q < 4; ++q)                             \
        GLOAD_LDS16(aG + (size_t)(kt) * 128 + (size_t)q * 32 * (H * 2),       \
                    smem + (buf) * 16384 + q * 4096 + tid * 16);

    // ---- B fragment loads: frag (n16b+ni, kt*2+kk), 1KB coalesced ----
    const int n16b = nt * 8 + wn * 4;
    const char* bF = (const char*)Bf + lane * 16;

#define BLOAD(dst, kt)                                                        \
    _Pragma("unroll") for (int ni = 0; ni < 4; ++ni)                          \
        _Pragma("unroll") for (int kk = 0; kk < 2; ++kk)                      \
            dst[ni * 2 + kk] = *(const bf16x8*)(bF +                          \
                (((size_t)(n16b + ni) * 32 + (size_t)(kt) * 2 + kk) << 10));

    // ---- A fragment read addressing (swizzled) ----
    const int rowA = wm * 64 + (lane & 15);
    const int xm = (lane & 7) << 4;
    const int c0 = (((lane >> 4) * 16)) ^ xm;
    const int c1 = (64 + ((lane >> 4) * 16)) ^ xm;

    f32x4 acc[4][4] = {};
    bf16x8 bA[8], bB[8];

#define TILE(cur, kt, BN_, DS_, bcur, bnext, VM)                              \
    {                                                                         \
        const char* aL = smem + (cur) * 16384;                                \
        asm volatile("s_waitcnt vmcnt(" VM ")" ::: "memory");                 \
        __builtin_amdgcn_s_barrier();                                         \
        __builtin_amdgcn_sched_barrier(0);                                    \
        if (BN_) BLOAD(bnext, (kt) + 1);                                      \
        bf16x8 a0[4], a1[4];                                                  \
        _Pragma("unroll") for (int mi = 0; mi < 4; ++mi) {                    \
            a0[mi] = *(const bf16x8*)(aL + (rowA + mi * 16) * 128 + c0);      \
            a1[mi] = *(const bf16x8*)(aL + (rowA + mi * 16) * 128 + c1);      \
        }                                                                     \
        asm volatile("s_waitcnt lgkmcnt(0)" ::: "memory");                    \
        __builtin_amdgcn_sched_barrier(0);    /* rule #18 fence */            \
        __builtin_amdgcn_s_barrier();         /* all A-reads of buf done */   \
        __builtin_amdgcn_sched_barrier(0);                                    \
        if (DS_) STAGE_A(cur, (kt) + 2);                                      \
        __builtin_amdgcn_s_setprio(1);                                        \
        _Pragma("unroll") for (int mi = 0; mi < 4; ++mi)                      \
            _Pragma("unroll") for (int ni = 0; ni < 4; ++ni)                  \
                acc[mi][ni] = __builtin_amdgcn_mfma_f32_16x16x32_bf16(        \
                    a0[mi], bcur[ni * 2 + 0], acc[mi][ni], 0, 0, 0);          \
        _Pragma("unroll") for (int mi = 0; mi < 4; ++mi)                      \
            _Pragma("unroll") for (int ni = 0; ni < 4; ++ni)                  \
                acc[mi][ni] = __builtin_amdgcn_mfma_f32_16x16x32_bf16(        \
                    a1[mi], bcur[ni * 2 + 1], acc[mi][ni], 0, 0, 0);          \
        __builtin_amdgcn_s_setprio(0);                                        \
    }

    // ---- prologue: B(0) first (oldest), then A(0), A(1) ----
    BLOAD(bA, 0);
    STAGE_A(0, 0);
    STAGE_A(1, 1);
    // TILE(0)'s vmcnt(4) forces B(0)+A(0), leaves A(1) in flight (steady state)

    // ---- main loop: ring-2 A, reg-dbuf B, seam vmcnt(4), never drained ----
    for (int kt = 0; kt < 12; kt += 2) {
        TILE(0, kt, 1, 1, bA, bB, "4");
        TILE(1, kt + 1, 1, 1, bB, bA, "4");
    }
    TILE(0, 12, 1, 1, bA, bB, "4");   // BLOAD 13, stages A(14)
    TILE(1, 13, 1, 1, bB, bA, "4");   // BLOAD 14, stages A(15)
    TILE(0, 14, 1, 0, bA, bB, "4");   // BLOAD 15
    TILE(1, 15, 0, 0, bB, bA, "0");

    // ---- epilogue: split q/k/v regions (wn*64 never straddles boundaries) ----
    const size_t QSZ = (size_t)rows * 1024;
    const size_t KSZ = (size_t)rows * 128;
    const int colg0 = nt * BN + wn * 64;
    float* op;
    int ldc, cb0;
    if (colg0 < 1024)      { op = out;             ldc = 1024; cb0 = colg0; }
    else if (colg0 < 1152) { op = out + QSZ;       ldc = 128;  cb0 = colg0 - 1024; }
    else                   { op = out + QSZ + KSZ; ldc = 128;  cb0 = colg0 - 1152; }

    const size_t r0 = m0 + wm * 64 + ((lane >> 4) * 4);
    const int cc0 = cb0 + (lane & 15);
#pragma unroll
    for (int mi = 0; mi < 4; ++mi)
#pragma unroll
        for (int ni = 0; ni < 4; ++ni)
#pragma unroll
            for (int rr = 0; rr < 4; ++rr)
                op[(r0 + mi * 16 + rr) * (size_t)ldc + cc0 + ni * 16] = acc[mi][ni][rr];
}

// ---------------------------------------------------------------------------
extern "C" void kernel_launch(void* const* d_in, const int* in_sizes, int n_in,
                              void* d_out, int out_size, void* d_ws, size_t ws_size,
                              hipStream_t stream) {
    const float* x   = (const float*)d_in[0];
    const float* lnw = (const float*)d_in[1];
    const float* wq  = (const float*)d_in[2];
    const float* wk  = (const float*)d_in[3];
    const float* wv  = (const float*)d_in[4];
    float* out = (float*)d_out;

    const int rows = in_sizes[0] / H;  // B*S = 32768

    __hip_bfloat16* Bf = (__hip_bfloat16*)d_ws;                               // 2.62 MB
    __hip_bfloat16* h  = (__hip_bfloat16*)((char*)d_ws + (size_t)NTOT * H * 2);

    const int nrms = rows / 4;  // 8192
    k_pre<<<nrms + 320, 256, 0, stream>>>(x, wq, wk, wv, lnw, h, Bf, nrms);
    k_gemm<<<(rows / BM) * NTILES, 256, 0, stream>>>(h, Bf, out, rows);
}